// Round 10
// baseline (198.238 us; speedup 1.0000x reference)
//
#include <hip/hip_runtime.h>
#include <stdint.h>

// ---------- types ----------
typedef __bf16 bf16x8 __attribute__((ext_vector_type(8)));
typedef float f32x4 __attribute__((ext_vector_type(4)));
typedef float float4v __attribute__((ext_vector_type(4)));
typedef unsigned short u16x8 __attribute__((ext_vector_type(8)));

// round-to-nearest-even fp32 -> bf16
__device__ __forceinline__ unsigned short f2bf(float f) {
    unsigned u = __float_as_uint(f);
    u += 0x7fffu + ((u >> 16) & 1u);
    return (unsigned short)(u >> 16);
}

// fast stable softplus: max(x,0) + log(1+exp(-|x|))
__device__ __forceinline__ float softplus(float x) {
    return fmaxf(x, 0.0f) + __logf(1.0f + __expf(-fabsf(x)));
}

// async global->LDS, 16B per lane (gfx950). LDS dest must be wave-uniform
// base + lane*16 (lane-ordered, contiguous).
__device__ __forceinline__ void gl_lds16(const void* gptr, void* lptr) {
    auto g = reinterpret_cast<const __attribute__((address_space(1))) void*>(
        reinterpret_cast<uintptr_t>(gptr));
    auto l = reinterpret_cast<__attribute__((address_space(3))) void*>(
        reinterpret_cast<uintptr_t>(lptr));
    __builtin_amdgcn_global_load_lds(g, l, 16, 0, 0);
}

// ---------- prep: WEIGHTS ONLY now.  w = mu + softplus(rho)*eps -> bf16 ----
// (input f32->bf16 conversion is fused into the GEMM's A-staging, deleting
//  its 48.8 MB of HBM traffic ~ 7.7 us)
__global__ void prep_kernel(const float* __restrict__ mu,
                            const float* __restrict__ rho,
                            const float* __restrict__ eps,
                            unsigned short* __restrict__ w_bf,
                            int nW8) {
    int j = blockIdx.x * blockDim.x + threadIdx.x;
    if (j >= nW8) return;
    const float4v* pm = (const float4v*)mu  + (size_t)j * 2;
    const float4v* pr = (const float4v*)rho + (size_t)j * 2;
    const float4v* pe = (const float4v*)eps + (size_t)j * 2;
    float4v m0 = pm[0], m1 = pm[1];
    float4v r0 = pr[0], r1 = pr[1];
    float4v e0 = pe[0], e1 = pe[1];
    u16x8 r;
    r[0] = f2bf(m0[0] + softplus(r0[0]) * e0[0]);
    r[1] = f2bf(m0[1] + softplus(r0[1]) * e0[1]);
    r[2] = f2bf(m0[2] + softplus(r0[2]) * e0[2]);
    r[3] = f2bf(m0[3] + softplus(r0[3]) * e0[3]);
    r[4] = f2bf(m1[0] + softplus(r1[0]) * e1[0]);
    r[5] = f2bf(m1[1] + softplus(r1[1]) * e1[1]);
    r[6] = f2bf(m1[2] + softplus(r1[2]) * e1[2]);
    r[7] = f2bf(m1[3] + softplus(r1[3]) * e1[3]);
    ((u16x8*)w_bf)[j] = r;
}

// ---------- GEMM: C[M,N] = A[M,K](f32!) * W[N,K]^T + bias, f32 out -------
// R10 = R8 (best measured: 40.9us, split-K 8 waves, 128^2 tile, BK=64 dbuf,
// single __syncthreads per window, 2 blocks/CU) + two additions:
//   1) FUSED A-CONVERSION (T14 issue-early/write-late): A staged from f32
//      input directly. Per thread per window: 4 global dwordx4 issued where
//      gl_lds used to be (before MFMAs), f2bf pack + 2 ds_write_b128 AFTER
//      the MFMAs (HBM latency hides under them), then the barrier. Bytes
//      written to LDS are bit-identical to the old prep+gl_lds path, so
//      fragment reads / swizzle / epilogue are untouched.
//   2) T1 XCD SWIZZLE (bijective, 512%8==0): swz=(orig&7)*64+(orig>>3);
//      each XCD owns 4 contiguous M-rows x all 16 N-cols -> its 4 f32
//      A-panels (4 MB) are L2-resident instead of 8 panels thrashing.
// Staging swizzle (R0/R4-verified, 0 conflicts): chunk c -> LDS slot c
// (row=c>>3, pkg=c&7); source k-group = pkg ^ (row&7); fragment reads use
// logical kg = kh*4+quad, phys = logical ^ (lane16&7).
#define BM 128
#define BN 128
#define BK 64
#define EX_S 66            // epilogue exchange row stride (floats)

__global__ __launch_bounds__(512, 4)
void gemm_bt_kernel(const float* __restrict__ A,            // [M,K] f32
                    const unsigned short* __restrict__ W,   // [N,K] bf16
                    const float* __restrict__ bias,         // [N]
                    float* __restrict__ C,                  // [M,N] f32
                    int M, int N, int K) {
    __shared__ unsigned short smem[32768];      // 64 KB total
    unsigned short* lds_a0 = smem;              // A buffers [0,16384)
    unsigned short* lds_b0 = smem + 16384;      // B buffers [16384,32768)

    const int t      = threadIdx.x;
    const int lane   = t & 63;
    const int wave   = t >> 6;          // 0..7
    const int lane16 = lane & 15;
    const int quad   = lane >> 4;       // 0..3
    const int wq     = wave & 3;        // spatial quadrant 0..3
    const int kh     = wave >> 2;       // K-half 0/1
    const int wm     = wq & 1;          // wave row: 0..1 (64 rows each)
    const int wn     = wq >> 1;         // wave col: 0..1 (64 cols each)

    // XCD-aware bijective block swizzle (grid must be 16 x 32 = 512)
    const int orig = blockIdx.y * gridDim.x + blockIdx.x;
    const int swz  = ((orig & 7) << 6) | (orig >> 3);
    const int m0 = (swz >> 4) * BM;     // 32 m-rows
    const int n0 = (swz & 15) * BN;     // 16 n-cols

    // staging geometry: 1024 16B-chunks per tile, 512 threads -> 2 each.
    const int r1   = t >> 3;                 // rows 0..63
    const int pkg1 = t & 7;
    const int g1   = (pkg1 ^ (r1 & 7)) * 8;
    const int r2   = r1 + 64;                // rows 64..127 (r2&7 == r1&7)
    const int g2   = (pkg1 ^ (r2 & 7)) * 8;

    const float*          Af = A + (size_t)m0 * K;
    const unsigned short* Wb = W + (size_t)n0 * K;

    f32x4 acc[4][4] = {};
    float4v ald[4];                     // in-flight A f32 (2 pieces x 16B x2)

    auto stageB = [&](int buf, int k0) {
        gl_lds16(Wb + (size_t)r1 * K + k0 + g1, lds_b0 + buf * 8192 + t * 8);
        gl_lds16(Wb + (size_t)r2 * K + k0 + g2, lds_b0 + buf * 8192 + 4096 + t * 8);
    };
    auto issueA = [&](int k0) {
        const float4v* p1 = (const float4v*)(Af + (size_t)r1 * K + k0 + g1);
        const float4v* p2 = (const float4v*)(Af + (size_t)r2 * K + k0 + g2);
        ald[0] = p1[0]; ald[1] = p1[1];
        ald[2] = p2[0]; ald[3] = p2[1];
    };
    auto writeA = [&](int buf) {
        u16x8 w0, w1;
#pragma unroll
        for (int j = 0; j < 4; ++j) {
            w0[j]     = f2bf(ald[0][j]);
            w0[j + 4] = f2bf(ald[1][j]);
            w1[j]     = f2bf(ald[2][j]);
            w1[j + 4] = f2bf(ald[3][j]);
        }
        *(u16x8*)(lds_a0 + buf * 8192 + t * 8)        = w0;
        *(u16x8*)(lds_a0 + buf * 8192 + 4096 + t * 8) = w1;
    };

    // fragment read offsets: logical k-group = kh*4+quad, phys = ^ (lane16&7)
    const int sw = lane16 & 7;
    const int raBase = (wm * 64 + lane16) * BK + (((kh * 4 + quad) ^ sw) * 8);
    const int rbBase = (wn * 64 + lane16) * BK + (((kh * 4 + quad) ^ sw) * 8);

    const int nit = K / BK;       // 32 (even)
    issueA(0);
    stageB(0, 0);
    writeA(0);
    __syncthreads();              // drain prologue staging (vm+lgkm)

    auto body = [&](int cur, int it) {
        const unsigned short* la = lds_a0 + cur * 8192;
        const unsigned short* lb = lds_b0 + cur * 8192;
        // (1) hoist ALL fragment reads for this wave's K-half
        bf16x8 af[4], bfr[4];
#pragma unroll
        for (int mi = 0; mi < 4; ++mi)
            af[mi] = *(const bf16x8*)(la + raBase + mi * 16 * BK);
#pragma unroll
        for (int ni = 0; ni < 4; ++ni)
            bfr[ni] = *(const bf16x8*)(lb + rbBase + ni * 16 * BK);
        // (2) issue NEXT window's staging: B async->LDS, A f32 -> regs
        if (it + 1 < nit) {
            stageB(cur ^ 1, (it + 1) * BK);
            issueA((it + 1) * BK);
        }
        // (3) MFMAs -- A-load latency and B gl_lds drain hide under these
#pragma unroll
        for (int mi = 0; mi < 4; ++mi)
#pragma unroll
            for (int ni = 0; ni < 4; ++ni)
                acc[mi][ni] = __builtin_amdgcn_mfma_f32_16x16x32_bf16(
                    af[mi], bfr[ni], acc[mi][ni], 0, 0, 0);
        // (3b) convert+write A for next window (waits its loads only here)
        if (it + 1 < nit) writeA(cur ^ 1);
        // (4) single barrier: staging drained AND current buffer released
        __syncthreads();
    };

    for (int it = 0; it < nit; it += 2) {
        body(0, it);
        body(1, it + 1);
    }
    // last body ended with __syncthreads: buffers free, all MFMAs done.

    // ---- cross-K-half reduction through LDS, 2 phases of 2 quadrants ----
    float* fs = (float*)smem;     // 16384 floats available
#pragma unroll
    for (int ph = 0; ph < 2; ++ph) {
        const bool mine = (wq >> 1) == ph;      // wq in {2ph, 2ph+1}
        const int rbase0 = (wq & 1) * (64 * EX_S);
        if (kh == 1 && mine) {
#pragma unroll
            for (int mi = 0; mi < 4; ++mi)
#pragma unroll
                for (int ni = 0; ni < 4; ++ni)
#pragma unroll
                    for (int rr = 0; rr < 4; ++rr)
                        fs[rbase0 + (mi * 16 + quad * 4 + rr) * EX_S +
                           ni * 16 + lane16] = acc[mi][ni][rr];
        }
        __syncthreads();
        if (kh == 0 && mine) {
#pragma unroll
            for (int mi = 0; mi < 4; ++mi)
#pragma unroll
                for (int ni = 0; ni < 4; ++ni)
#pragma unroll
                    for (int rr = 0; rr < 4; ++rr)
                        acc[mi][ni][rr] += fs[rbase0 +
                            (mi * 16 + quad * 4 + rr) * EX_S + ni * 16 + lane16];
        }
        __syncthreads();
    }

    if (kh != 0) return;          // upper waves done (all barriers passed)

    // epilogue: C/D layout col=lane&15, row=quad*4+reg (m89-verified)
    float bv[4];
#pragma unroll
    for (int ni = 0; ni < 4; ++ni)
        bv[ni] = bias[n0 + wn * 64 + ni * 16 + lane16];

#pragma unroll
    for (int mi = 0; mi < 4; ++mi) {
        const int rbase = m0 + wm * 64 + mi * 16 + quad * 4;
#pragma unroll
        for (int ni = 0; ni < 4; ++ni) {
            const int col = n0 + wn * 64 + ni * 16 + lane16;
#pragma unroll
            for (int rr = 0; rr < 4; ++rr)
                C[(size_t)(rbase + rr) * N + col] = acc[mi][ni][rr] + bv[ni];
        }
    }
}

extern "C" void kernel_launch(void* const* d_in, const int* in_sizes, int n_in,
                              void* d_out, int out_size, void* d_ws, size_t ws_size,
                              hipStream_t stream) {
    const float* input = (const float*)d_in[0];
    const float* mu    = (const float*)d_in[1];
    const float* rho   = (const float*)d_in[2];
    const float* eps   = (const float*)d_in[3];
    const float* bias  = (const float*)d_in[4];
    float* out = (float*)d_out;

    const int OUT = in_sizes[4];              // 2048
    const int IN  = in_sizes[1] / OUT;        // 2048
    const int M   = in_sizes[0] / IN;         // 4096

    unsigned short* w_bf = (unsigned short*)d_ws;      // OUT*IN bf16 only

    const int nW8 = (OUT * IN) / 8;
    prep_kernel<<<dim3((nW8 + 255) / 256), 256, 0, stream>>>(
        mu, rho, eps, w_bf, nW8);

    gemm_bt_kernel<<<dim3(OUT / BN, M / BM), 512, 0, stream>>>(
        input, w_bf, bias, out, M, OUT, IN);
}

// Round 11
// 159.573 us; speedup vs baseline: 1.2423x; 1.2423x over previous
//
#include <hip/hip_runtime.h>
#include <stdint.h>

// ---------- types ----------
typedef __bf16 bf16x8 __attribute__((ext_vector_type(8)));
typedef float f32x4 __attribute__((ext_vector_type(4)));
typedef float float4v __attribute__((ext_vector_type(4)));
typedef unsigned short u16x8 __attribute__((ext_vector_type(8)));

// round-to-nearest-even fp32 -> bf16
__device__ __forceinline__ unsigned short f2bf(float f) {
    unsigned u = __float_as_uint(f);
    u += 0x7fffu + ((u >> 16) & 1u);
    return (unsigned short)(u >> 16);
}

// fast stable softplus: max(x,0) + log(1+exp(-|x|))
__device__ __forceinline__ float softplus(float x) {
    return fmaxf(x, 0.0f) + __logf(1.0f + __expf(-fabsf(x)));
}

// async global->LDS, 16B per lane (gfx950). LDS dest must be wave-uniform
// base + lane*16 (lane-ordered, contiguous).
__device__ __forceinline__ void gl_lds16(const void* gptr, void* lptr) {
    auto g = reinterpret_cast<const __attribute__((address_space(1))) void*>(
        reinterpret_cast<uintptr_t>(gptr));
    auto l = reinterpret_cast<__attribute__((address_space(3))) void*>(
        reinterpret_cast<uintptr_t>(lptr));
    __builtin_amdgcn_global_load_lds(g, l, 16, 0, 0);
}

// ---------- fused prep: input f32->bf16  AND  w = mu + softplus(rho)*eps ----
// (R10's in-GEMM A-conversion reverted: it put vmcnt-wait + convert + LDS
//  write on the gemm critical path -> 2.4x regression. Prep is at its own
//  HBM roofline; this split is optimal for the 2-kernel layout.)
__global__ void prep_kernel(const float* __restrict__ in,
                            const float* __restrict__ mu,
                            const float* __restrict__ rho,
                            const float* __restrict__ eps,
                            unsigned short* __restrict__ in_bf,
                            unsigned short* __restrict__ w_bf,
                            int nIn8, int nW8) {
    int i = blockIdx.x * blockDim.x + threadIdx.x;
    if (i < nIn8) {
        const float4v* p = (const float4v*)in + (size_t)i * 2;
        float4v a = p[0], b = p[1];
        u16x8 r;
        r[0] = f2bf(a[0]); r[1] = f2bf(a[1]); r[2] = f2bf(a[2]); r[3] = f2bf(a[3]);
        r[4] = f2bf(b[0]); r[5] = f2bf(b[1]); r[6] = f2bf(b[2]); r[7] = f2bf(b[3]);
        ((u16x8*)in_bf)[i] = r;
    } else {
        int j = i - nIn8;
        if (j >= nW8) return;
        const float4v* pm = (const float4v*)mu  + (size_t)j * 2;
        const float4v* pr = (const float4v*)rho + (size_t)j * 2;
        const float4v* pe = (const float4v*)eps + (size_t)j * 2;
        float4v m0 = pm[0], m1 = pm[1];
        float4v r0 = pr[0], r1 = pr[1];
        float4v e0 = pe[0], e1 = pe[1];
        u16x8 r;
        r[0] = f2bf(m0[0] + softplus(r0[0]) * e0[0]);
        r[1] = f2bf(m0[1] + softplus(r0[1]) * e0[1]);
        r[2] = f2bf(m0[2] + softplus(r0[2]) * e0[2]);
        r[3] = f2bf(m0[3] + softplus(r0[3]) * e0[3]);
        r[4] = f2bf(m1[0] + softplus(r1[0]) * e1[0]);
        r[5] = f2bf(m1[1] + softplus(r1[1]) * e1[1]);
        r[6] = f2bf(m1[2] + softplus(r1[2]) * e1[2]);
        r[7] = f2bf(m1[3] + softplus(r1[3]) * e1[3]);
        ((u16x8*)w_bf)[j] = r;
    }
}

// ---------- GEMM: C[M,N] = A[M,K] * B[N,K]^T + bias, bf16 in / f32 out -----
// R11 = R8 VERBATIM (session best: gemm 40.9us, split-K 8 waves = 2x2
// spatial x 2 K-halves, 128^2 tile, BK=64 dbuf, single __syncthreads per
// window, 2 blocks/CU) + ONE change: bijective XCD block swizzle (T1).
//   Grid = 512 blocks = 8 XCDs x 64. Default round-robin makes each XCD
//   touch all 32 A-panels (16 MB through its 4 MB L2 -> thrash; gl_lds
//   staging at HBM latency ~900cy feeds the per-window barrier drain).
//   swz = (orig&7)*64 + orig>>3 gives each XCD 4 contiguous m-tiles x all
//   16 n-tiles: A working set 2 MB = L2-resident -> staging at L2 latency
//   ~200cy -> shorter drain. Single-variable A/B vs R8's measured 40.9.
#define BM 128
#define BN 128
#define BK 64
#define EX_S 66            // epilogue exchange row stride (floats)

__global__ __launch_bounds__(512, 4)
void gemm_bt_kernel(const unsigned short* __restrict__ A,   // [M,K] bf16
                    const unsigned short* __restrict__ B,   // [N,K] bf16
                    const float* __restrict__ bias,         // [N]
                    float* __restrict__ C,                  // [M,N] f32
                    int M, int N, int K) {
    __shared__ unsigned short smem[32768];      // 64 KB total
    unsigned short* lds_a0 = smem;              // A buffers [0,16384)
    unsigned short* lds_b0 = smem + 16384;      // B buffers [16384,32768)

    const int t      = threadIdx.x;
    const int lane   = t & 63;
    const int wave   = t >> 6;          // 0..7
    const int lane16 = lane & 15;
    const int quad   = lane >> 4;       // 0..3
    const int wq     = wave & 3;        // spatial quadrant 0..3
    const int kh     = wave >> 2;       // K-half 0/1
    const int wm     = wq & 1;          // wave row: 0..1 (64 rows each)
    const int wn     = wq >> 1;         // wave col: 0..1 (64 cols each)

    // T1: bijective XCD swizzle (512 blocks, 512 % 8 == 0)
    const int orig = blockIdx.y * gridDim.x + blockIdx.x;   // 0..511
    const int swz  = ((orig & 7) << 6) | (orig >> 3);
    const int m0 = (swz >> 4) * BM;     // 32 m-tiles
    const int n0 = (swz & 15) * BN;     // 16 n-tiles

    // staging: 1024 16B-chunks per tile, 512 threads -> 2 chunks each.
    // chunk c -> LDS slot c (row = c>>3, pkg = c&7); global kg = pkg ^ (row&7)
    const int r1   = t >> 3;                 // rows 0..63
    const int pkg1 = t & 7;
    const int g1   = (pkg1 ^ (r1 & 7)) * 8;
    const int r2   = r1 + 64;                // rows 64..127 (r2&7 == r1&7)
    const int g2   = (pkg1 ^ (r2 & 7)) * 8;

    const unsigned short* Ab = A + (size_t)m0 * K;
    const unsigned short* Bb = B + (size_t)n0 * K;

    f32x4 acc[4][4] = {};

    auto stage = [&](int buf, int k0) {
        gl_lds16(Ab + (size_t)r1 * K + k0 + g1, lds_a0 + buf * 8192 + t * 8);
        gl_lds16(Ab + (size_t)r2 * K + k0 + g2, lds_a0 + buf * 8192 + 4096 + t * 8);
        gl_lds16(Bb + (size_t)r1 * K + k0 + g1, lds_b0 + buf * 8192 + t * 8);
        gl_lds16(Bb + (size_t)r2 * K + k0 + g2, lds_b0 + buf * 8192 + 4096 + t * 8);
    };

    // fragment read offsets: row = (wm|wn)*64 + base + lane16, logical
    // k-group = kh*4 + quad, phys = logical ^ (row&7) = logical ^ (lane16&7)
    const int sw = lane16 & 7;
    const int raBase = (wm * 64 + lane16) * BK + (((kh * 4 + quad) ^ sw) * 8);
    const int rbBase = (wn * 64 + lane16) * BK + (((kh * 4 + quad) ^ sw) * 8);

    const int nit = K / BK;       // 32 (even)
    stage(0, 0);
    __syncthreads();              // drain prologue staging

    auto body = [&](int cur, int it) {
        const unsigned short* la = lds_a0 + cur * 8192;
        const unsigned short* lb = lds_b0 + cur * 8192;
        // (1) hoist ALL fragment reads for this wave's K-half
        bf16x8 af[4], bfr[4];
#pragma unroll
        for (int mi = 0; mi < 4; ++mi)
            af[mi] = *(const bf16x8*)(la + raBase + mi * 16 * BK);
#pragma unroll
        for (int ni = 0; ni < 4; ++ni)
            bfr[ni] = *(const bf16x8*)(lb + rbBase + ni * 16 * BK);
        // (2) async-stage NEXT buffer (no alias with reads)
        if (it + 1 < nit) stage(cur ^ 1, (it + 1) * BK);
        // (3) MFMAs -- vmcnt drain at the barrier lands after these
#pragma unroll
        for (int mi = 0; mi < 4; ++mi)
#pragma unroll
            for (int ni = 0; ni < 4; ++ni)
                acc[mi][ni] = __builtin_amdgcn_mfma_f32_16x16x32_bf16(
                    af[mi], bfr[ni], acc[mi][ni], 0, 0, 0);
        // (4) single barrier: next-staging drained AND current buffer released
        __syncthreads();
    };

    for (int it = 0; it < nit; it += 2) {
        body(0, it);
        body(1, it + 1);
    }
    // last body ended with __syncthreads: buffers free, all MFMAs done.

    // ---- cross-K-half reduction through LDS, 2 phases of 2 quadrants ----
    float* fs = (float*)smem;     // 16384 floats available
#pragma unroll
    for (int ph = 0; ph < 2; ++ph) {
        const bool mine = (wq >> 1) == ph;      // wq in {2ph, 2ph+1}
        const int rbase0 = (wq & 1) * (64 * EX_S);
        if (kh == 1 && mine) {
#pragma unroll
            for (int mi = 0; mi < 4; ++mi)
#pragma unroll
                for (int ni = 0; ni < 4; ++ni)
#pragma unroll
                    for (int rr = 0; rr < 4; ++rr)
                        fs[rbase0 + (mi * 16 + quad * 4 + rr) * EX_S +
                           ni * 16 + lane16] = acc[mi][ni][rr];
        }
        __syncthreads();
        if (kh == 0 && mine) {
#pragma unroll
            for (int mi = 0; mi < 4; ++mi)
#pragma unroll
                for (int ni = 0; ni < 4; ++ni)
#pragma unroll
                    for (int rr = 0; rr < 4; ++rr)
                        acc[mi][ni][rr] += fs[rbase0 +
                            (mi * 16 + quad * 4 + rr) * EX_S + ni * 16 + lane16];
        }
        __syncthreads();
    }

    if (kh != 0) return;          // upper waves done (all barriers passed)

    // epilogue: C/D layout col=lane&15, row=quad*4+reg (m89-verified)
    float bv[4];
#pragma unroll
    for (int ni = 0; ni < 4; ++ni)
        bv[ni] = bias[n0 + wn * 64 + ni * 16 + lane16];

#pragma unroll
    for (int mi = 0; mi < 4; ++mi) {
        const int rbase = m0 + wm * 64 + mi * 16 + quad * 4;
#pragma unroll
        for (int ni = 0; ni < 4; ++ni) {
            const int col = n0 + wn * 64 + ni * 16 + lane16;
#pragma unroll
            for (int rr = 0; rr < 4; ++rr)
                C[(size_t)(rbase + rr) * N + col] = acc[mi][ni][rr] + bv[ni];
        }
    }
}

extern "C" void kernel_launch(void* const* d_in, const int* in_sizes, int n_in,
                              void* d_out, int out_size, void* d_ws, size_t ws_size,
                              hipStream_t stream) {
    const float* input = (const float*)d_in[0];
    const float* mu    = (const float*)d_in[1];
    const float* rho   = (const float*)d_in[2];
    const float* eps   = (const float*)d_in[3];
    const float* bias  = (const float*)d_in[4];
    float* out = (float*)d_out;

    const int OUT = in_sizes[4];              // 2048
    const int IN  = in_sizes[1] / OUT;        // 2048
    const int M   = in_sizes[0] / IN;         // 4096

    unsigned short* in_bf = (unsigned short*)d_ws;                 // M*IN bf16
    unsigned short* w_bf  = in_bf + (size_t)M * IN;                // OUT*IN bf16

    const int nIn8 = (M * IN) / 8;
    const int nW8  = (OUT * IN) / 8;
    prep_kernel<<<dim3((nIn8 + nW8 + 255) / 256), 256, 0, stream>>>(
        input, mu, rho, eps, in_bf, w_bf, nIn8, nW8);

    gemm_bt_kernel<<<dim3(OUT / BN, M / BM), 512, 0, stream>>>(
        in_bf, w_bf, bias, out, M, OUT, IN);
}